// Round 8
// baseline (202.190 us; speedup 1.0000x reference)
//
#include <hip/hip_runtime.h>
#include <hip/hip_bf16.h>
#include <cstdint>
#include <cstddef>

typedef __attribute__((ext_vector_type(8))) short short8;
typedef __attribute__((ext_vector_type(4))) float f32x4;

#define S_LEN 2048
#define EMB 384
#define NH 6
#define HD 64
#define NB 8
// Q pre-scale: (1/sqrt(64)) * log2(e) so attn uses exp2 directly
#define QSCALE 0.180336880f

__device__ __forceinline__ unsigned short f2bf(float f) {
  return __builtin_bit_cast(unsigned short, __float2bfloat16(f));
}

// ---------------- prep: coalesced LDS W-transpose only ----------------
__global__ __launch_bounds__(256) void k_prepw(
    const float* __restrict__ Wq, const float* __restrict__ Wk,
    const float* __restrict__ Wv, const float* __restrict__ Wo,
    unsigned short* __restrict__ Wqt, unsigned short* __restrict__ Wkt,
    unsigned short* __restrict__ Wvt, unsigned short* __restrict__ Wot) {
  __shared__ unsigned short Lw[64 * 66];
  const int tid = threadIdx.x;
  const int bx2 = blockIdx.x;            // 0..143
  const int mat = bx2 / 36;
  const int tile = bx2 - mat * 36;
  const int k0 = (tile / 6) * 64;
  const int n0 = (tile % 6) * 64;
  const float* W = (mat == 0) ? Wq : (mat == 1) ? Wk : (mat == 2) ? Wv : Wo;
  unsigned short* Wt = (mat == 0) ? Wqt : (mat == 1) ? Wkt : (mat == 2) ? Wvt : Wot;
  const int f4 = tid & 15;
#pragma unroll
  for (int it = 0; it < 4; ++it) {
    const int kl = it * 16 + (tid >> 4);
    const float4 v = reinterpret_cast<const float4*>(W + (size_t)(k0 + kl) * EMB + n0)[f4];
    Lw[kl * 66 + f4 * 4 + 0] = f2bf(v.x);
    Lw[kl * 66 + f4 * 4 + 1] = f2bf(v.y);
    Lw[kl * 66 + f4 * 4 + 2] = f2bf(v.z);
    Lw[kl * 66 + f4 * 4 + 3] = f2bf(v.w);
  }
  __syncthreads();
  const int g = tid & 7;
#pragma unroll
  for (int it = 0; it < 2; ++it) {
    const int nl = it * 32 + (tid >> 3);
    short8 o;
#pragma unroll
    for (int j = 0; j < 8; ++j) o[j] = (short)Lw[(g * 8 + j) * 66 + nl];
    *reinterpret_cast<short8*>(Wt + (size_t)(n0 + nl) * EMB + k0 + g * 8) = o;
  }
}

// ---------------- fused QKV projection GEMM ----------------
// Reads x fp32 directly (inline bf16 convert in staging). XCD swizzle.
// Q (pre-scaled) / K: vectorized epilogue via LDS repack. V: direct-transposed store.
__global__ __launch_bounds__(256) void k_qkv(
    const float* __restrict__ x,
    const unsigned short* __restrict__ Wqt,
    const unsigned short* __restrict__ Wkt,
    const unsigned short* __restrict__ Wvt,
    unsigned short* __restrict__ Qb,
    unsigned short* __restrict__ Kb,
    unsigned short* __restrict__ Vtb) {
  __shared__ __attribute__((aligned(16))) unsigned short La[128 * 72];   // A k-tile, pad 72
  __shared__ __attribute__((aligned(16))) unsigned short Lt[64 * 136];   // repack buffer

  const int tid = threadIdx.x;
  const int lane = tid & 63;
  const int w = tid >> 6;
  const int wr = w >> 1, wc = w & 1;
  const int lr = lane & 15, lg = lane >> 4;

  const int bid = blockIdx.y * 128 + blockIdx.x;
  const int xcd = bid & 7;
  const int pos = bid >> 3;            // 0..143
  const int bx = xcd * 16 + (pos & 15);
  const int by = pos >> 4;             // 0..8
  const int m0 = bx * 128;
  const int wsel = by / 3;
  const int n0 = (by % 3) * 128;
  const unsigned short* Wt = (wsel == 0) ? Wqt : (wsel == 1) ? Wkt : Wvt;

  const int srow = tid >> 3;       // 0..31
  const int sg = tid & 7;          // 16B slot

  f32x4 acc[4][4] = {};
  float4 xf[4][2];
  short8 breg[2][2][4];            // [parity][kk][frag]

  // prologue: tile 0 A (fp32) + B
#pragma unroll
  for (int i = 0; i < 4; ++i) {
    const float* src = x + (size_t)(m0 + i * 32 + srow) * EMB + sg * 8;
    xf[i][0] = *reinterpret_cast<const float4*>(src);
    xf[i][1] = *reinterpret_cast<const float4*>(src + 4);
  }
#pragma unroll
  for (int kk = 0; kk < 2; ++kk)
#pragma unroll
    for (int ns = 0; ns < 4; ++ns)
      breg[0][kk][ns] = *reinterpret_cast<const short8*>(
          Wt + (size_t)(n0 + wc * 64 + ns * 16 + lr) * EMB + kk * 32 + lg * 8);

#pragma unroll
  for (int kt = 0; kt < 6; ++kt) {
    const int cur = kt & 1, nxt = cur ^ 1;
    __syncthreads();
#pragma unroll
    for (int i = 0; i < 4; ++i) {
      short8 v;
      v[0] = (short)f2bf(xf[i][0].x); v[1] = (short)f2bf(xf[i][0].y);
      v[2] = (short)f2bf(xf[i][0].z); v[3] = (short)f2bf(xf[i][0].w);
      v[4] = (short)f2bf(xf[i][1].x); v[5] = (short)f2bf(xf[i][1].y);
      v[6] = (short)f2bf(xf[i][1].z); v[7] = (short)f2bf(xf[i][1].w);
      *reinterpret_cast<short8*>(&La[(i * 32 + srow) * 72 + sg * 8]) = v;
    }
    __syncthreads();
    if (kt < 5) {
      const int kn = (kt + 1) * 64;
#pragma unroll
      for (int i = 0; i < 4; ++i) {
        const float* src = x + (size_t)(m0 + i * 32 + srow) * EMB + kn + sg * 8;
        xf[i][0] = *reinterpret_cast<const float4*>(src);
        xf[i][1] = *reinterpret_cast<const float4*>(src + 4);
      }
#pragma unroll
      for (int kk = 0; kk < 2; ++kk)
#pragma unroll
        for (int ns = 0; ns < 4; ++ns)
          breg[nxt][kk][ns] = *reinterpret_cast<const short8*>(
              Wt + (size_t)(n0 + wc * 64 + ns * 16 + lr) * EMB + kn + kk * 32 + lg * 8);
    }
#pragma unroll
    for (int kk = 0; kk < 2; ++kk) {
      short8 a[4];
#pragma unroll
      for (int ms = 0; ms < 4; ++ms)
        a[ms] = *reinterpret_cast<const short8*>(
            &La[(wr * 64 + ms * 16 + lr) * 72 + kk * 32 + lg * 8]);
#pragma unroll
      for (int ms = 0; ms < 4; ++ms)
#pragma unroll
        for (int ns = 0; ns < 4; ++ns)
          acc[ms][ns] = __builtin_amdgcn_mfma_f32_16x16x32_bf16(
              a[ms], breg[cur][kk][ns], acc[ms][ns], 0, 0, 0);
    }
  }

  const int bb = m0 >> 11;
  const int s0 = m0 & 2047;
  if (wsel != 2) {
    // Q/K: LDS repack -> coalesced short8 stores
    unsigned short* Out = (wsel == 0) ? Qb : Kb;
    const float sc = (wsel == 0) ? QSCALE : 1.0f;
#pragma unroll
    for (int p = 0; p < 2; ++p) {
      __syncthreads();
      if (wr == p) {
#pragma unroll
        for (int ms = 0; ms < 4; ++ms)
#pragma unroll
          for (int ns = 0; ns < 4; ++ns)
#pragma unroll
            for (int r = 0; r < 4; ++r)
              Lt[(ms * 16 + lg * 4 + r) * 136 + wc * 64 + ns * 16 + lr] =
                  f2bf(acc[ms][ns][r] * sc);
      }
      __syncthreads();
#pragma unroll
      for (int it = 0; it < 4; ++it) {
        const int row = (tid >> 3) + 32 * (it & 1);
        const int ch = (tid & 7) + 8 * (it >> 1);
        const short8 v = *reinterpret_cast<const short8*>(&Lt[row * 136 + ch * 8]);
        const int n = n0 + ch * 8;
        const int h = n >> 6, d = n & 63;
        *reinterpret_cast<short8*>(
            Out + (((size_t)bb * NH + h) * S_LEN + (s0 + p * 64 + row)) * HD + d) = v;
      }
    }
  } else {
    // V: repack via LDS -> coalesced transposed store [b,h,d,s]
#pragma unroll
    for (int p = 0; p < 2; ++p) {
      __syncthreads();
      if (wc == p) {
#pragma unroll
        for (int ms = 0; ms < 4; ++ms)
#pragma unroll
          for (int ns = 0; ns < 4; ++ns)
#pragma unroll
            for (int r = 0; r < 4; ++r) {
              const int dl = ns * 16 + lr;                     // d 0..63
              const int ml = wr * 64 + ms * 16 + lg * 4 + r;   // m 0..127
              Lt[dl * 136 + (((ml >> 3) ^ (dl & 7)) << 3) + (ml & 7)] = f2bf(acc[ms][ns][r]);
            }
      }
      __syncthreads();
      const int hg = 2 * (n0 >> 7) + p;
      const int c = tid & 15;
#pragma unroll
      for (int it = 0; it < 4; ++it) {
        const int d = it * 16 + (tid >> 4);
        const short8 v = *reinterpret_cast<const short8*>(
            &Lt[d * 136 + ((c ^ (d & 7)) << 3)]);
        *reinterpret_cast<short8*>(
            Vtb + (((size_t)bb * NH + hg) * HD + d) * S_LEN + s0 + c * 8) = v;
      }
    }
  }
}

// ---------------- causal flash attention (KVBLK=64, swizzled LDS, no-max softmax) ----
// grid 768 XCD-swizzled; block 256 = 4 waves x 16 q-rows; paired q-tiles (33 KV each).
__global__ __launch_bounds__(256) void k_attn(
    const unsigned short* __restrict__ Qb,
    const unsigned short* __restrict__ Kb,
    const unsigned short* __restrict__ Vtg,
    unsigned short* __restrict__ Ob) {
  __shared__ __attribute__((aligned(16))) unsigned short Ks[64 * 64];
  __shared__ __attribute__((aligned(16))) unsigned short Vt[64 * 64];
  __shared__ __attribute__((aligned(16))) unsigned short Ps[64 * 64];

  const int tid = threadIdx.x;
  const int lane = tid & 63;
  const int w = tid >> 6;
  const int lr = lane & 15, lg = lane >> 4;

  const int lin = blockIdx.y * 16 + blockIdx.x;
  const int swz = (lin & 7) * 96 + (lin >> 3);
  const int pair = swz & 15;
  const int bh = swz >> 4;

  const unsigned short* Qp = Qb + (size_t)bh * S_LEN * HD;
  const unsigned short* Kp = Kb + (size_t)bh * S_LEN * HD;
  const unsigned short* Vp = Vtg + (size_t)bh * S_LEN * HD;
  const int b = bh / NH, hh = bh - b * NH;

  const int srow = tid >> 3;
  const int sslot = tid & 7;
  const int wsl0 = (sslot ^ (srow & 7)) << 3;

  for (int phase = 0; phase < 2; ++phase) {
    const int qt = phase ? (31 - pair) : pair;
    const int qbase = qt * 64 + w * 16;

    const short8 aq0 = *reinterpret_cast<const short8*>(Qp + (size_t)(qbase + lr) * HD + lg * 8);
    const short8 aq1 = *reinterpret_cast<const short8*>(Qp + (size_t)(qbase + lr) * HD + 32 + lg * 8);

    f32x4 o[4] = {};
    float l_i[4] = {0.f, 0.f, 0.f, 0.f};

    short8 pk0 = *reinterpret_cast<const short8*>(Kp + (size_t)srow * HD + sslot * 8);
    short8 pk1 = *reinterpret_cast<const short8*>(Kp + (size_t)(srow + 32) * HD + sslot * 8);
    short8 pv0 = *reinterpret_cast<const short8*>(Vp + (size_t)srow * S_LEN + sslot * 8);
    short8 pv1 = *reinterpret_cast<const short8*>(Vp + (size_t)(srow + 32) * S_LEN + sslot * 8);

    for (int t = 0; t <= qt; ++t) {
      __syncthreads();
      *reinterpret_cast<short8*>(&Ks[srow * 64 + wsl0]) = pk0;
      *reinterpret_cast<short8*>(&Ks[(srow + 32) * 64 + wsl0]) = pk1;
      *reinterpret_cast<short8*>(&Vt[srow * 64 + wsl0]) = pv0;
      *reinterpret_cast<short8*>(&Vt[(srow + 32) * 64 + wsl0]) = pv1;
      __syncthreads();

      if (t < qt) {
        const int tn = (t + 1) * 64;
        pk0 = *reinterpret_cast<const short8*>(Kp + (size_t)(tn + srow) * HD + sslot * 8);
        pk1 = *reinterpret_cast<const short8*>(Kp + (size_t)(tn + srow + 32) * HD + sslot * 8);
        pv0 = *reinterpret_cast<const short8*>(Vp + (size_t)srow * S_LEN + tn + sslot * 8);
        pv1 = *reinterpret_cast<const short8*>(Vp + (size_t)(srow + 32) * S_LEN + tn + sslot * 8);
      }

      float sv[4][4];
#pragma unroll
      for (int ks = 0; ks < 4; ++ks) {
        const int kstart = t * 64 + ks * 16;
        if (kstart > qbase + 15) {
#pragma unroll
          for (int r = 0; r < 4; ++r) sv[ks][r] = -1e30f;
        } else {
          const int krow = ks * 16 + lr;
          const int kx = krow & 7;
          const short8 bk0 = *reinterpret_cast<const short8*>(&Ks[krow * 64 + ((lg ^ kx) << 3)]);
          const short8 bk1 = *reinterpret_cast<const short8*>(&Ks[krow * 64 + (((4 + lg) ^ kx) << 3)]);
          f32x4 s = {};
          s = __builtin_amdgcn_mfma_f32_16x16x32_bf16(aq0, bk0, s, 0, 0, 0);
          s = __builtin_amdgcn_mfma_f32_16x16x32_bf16(aq1, bk1, s, 0, 0, 0);
          if (kstart + 15 <= qbase) {
#pragma unroll
            for (int r = 0; r < 4; ++r) sv[ks][r] = s[r];
          } else {
            const int kg = kstart + lr;
#pragma unroll
            for (int r = 0; r < 4; ++r)
              sv[ks][r] = (kg <= qbase + lg * 4 + r) ? s[r] : -1e30f;
          }
        }
      }

#pragma unroll
      for (int r = 0; r < 4; ++r) {
        const int q = w * 16 + lg * 4 + r;
        const int qx = q & 7;
        const int abase = q * 64 + (lr & 7);
        const int sp = lr >> 3;
        float p[4];
#pragma unroll
        for (int ks = 0; ks < 4; ++ks) p[ks] = __builtin_amdgcn_exp2f(sv[ks][r]);
        l_i[r] += (p[0] + p[1]) + (p[2] + p[3]);
#pragma unroll
        for (int ks = 0; ks < 4; ++ks)
          Ps[abase + ((((ks << 1) | sp) ^ qx) << 3)] = f2bf(p[ks]);
      }

      const int qrow = w * 16 + lr;
      const int qx2 = qrow & 7;
#pragma unroll
      for (int kk = 0; kk < 2; ++kk) {
        const short8 ap = *reinterpret_cast<const short8*>(
            &Ps[qrow * 64 + (((kk * 4 + lg) ^ qx2) << 3)]);
#pragma unroll
        for (int ns = 0; ns < 4; ++ns) {
          const int vrow = ns * 16 + lr;
          const short8 bv = *reinterpret_cast<const short8*>(
              &Vt[vrow * 64 + (((kk * 4 + lg) ^ (vrow & 7)) << 3)]);
          o[ns] = __builtin_amdgcn_mfma_f32_16x16x32_bf16(ap, bv, o[ns], 0, 0, 0);
        }
      }
    }

#pragma unroll
    for (int r = 0; r < 4; ++r) {
      float l = l_i[r];
      l += __shfl_xor(l, 1);
      l += __shfl_xor(l, 2);
      l += __shfl_xor(l, 4);
      l += __shfl_xor(l, 8);
      l_i[r] = 1.0f / l;
    }
#pragma unroll
    for (int ns = 0; ns < 4; ++ns)
#pragma unroll
      for (int r = 0; r < 4; ++r) {
        const int qg = qbase + lg * 4 + r;
        const float val = o[ns][r] * l_i[r];
        Ob[((size_t)(b * S_LEN + qg)) * EMB + hh * HD + ns * 16 + lr] = f2bf(val);
      }
  }
}

// ---------------- output projection (BM=64, vectorized epilogue) ----------------
__global__ __launch_bounds__(256) void k_oproj(
    const unsigned short* __restrict__ Ob,
    const unsigned short* __restrict__ Wot,
    const float* __restrict__ bo,
    float* __restrict__ out) {
  __shared__ __attribute__((aligned(16))) unsigned short La[64 * 72];
  __shared__ __attribute__((aligned(16))) float Lf[64 * 132];

  const int tid = threadIdx.x;
  const int lane = tid & 63;
  const int w = tid >> 6;
  const int lr = lane & 15, lg = lane >> 4;

  const int bid = blockIdx.y * 256 + blockIdx.x;
  const int xcd = bid & 7;
  const int pos = bid >> 3;            // 0..95
  const int m0 = (xcd * 32 + (pos & 31)) * 64;
  const int n0 = (pos >> 5) * 128;

  const int srow = tid >> 3;       // 0..31
  const int sg = tid & 7;

  f32x4 acc[4][2] = {};
  short8 st[2];
  short8 breg[2][2][2];            // [parity][kk][ns]

#pragma unroll
  for (int i = 0; i < 2; ++i)
    st[i] = *reinterpret_cast<const short8*>(
        Ob + (size_t)(m0 + i * 32 + srow) * EMB + sg * 8);
#pragma unroll
  for (int kk = 0; kk < 2; ++kk)
#pragma unroll
    for (int ns = 0; ns < 2; ++ns)
      breg[0][kk][ns] = *reinterpret_cast<const short8*>(
          Wot + (size_t)(n0 + w * 32 + ns * 16 + lr) * EMB + kk * 32 + lg * 8);

#pragma unroll
  for (int kt = 0; kt < 6; ++kt) {
    const int cur = kt & 1, nxt = cur ^ 1;
    __syncthreads();
#pragma unroll
    for (int i = 0; i < 2; ++i)
      *reinterpret_cast<short8*>(&La[(i * 32 + srow) * 72 + sg * 8]) = st[i];
    __syncthreads();
    if (kt < 5) {
      const int kn = (kt + 1) * 64;
#pragma unroll
      for (int i = 0; i < 2; ++i)
        st[i] = *reinterpret_cast<const short8*>(
            Ob + (size_t)(m0 + i * 32 + srow) * EMB + kn + sg * 8);
#pragma unroll
      for (int kk = 0; kk < 2; ++kk)
#pragma unroll
        for (int ns = 0; ns < 2; ++ns)
          breg[nxt][kk][ns] = *reinterpret_cast<const short8*>(
              Wot + (size_t)(n0 + w * 32 + ns * 16 + lr) * EMB + kn + kk * 32 + lg * 8);
    }
#pragma unroll
    for (int kk = 0; kk < 2; ++kk) {
      short8 a[4];
#pragma unroll
      for (int ms = 0; ms < 4; ++ms)
        a[ms] = *reinterpret_cast<const short8*>(
            &La[(ms * 16 + lr) * 72 + kk * 32 + lg * 8]);
#pragma unroll
      for (int ms = 0; ms < 4; ++ms)
#pragma unroll
        for (int ns = 0; ns < 2; ++ns)
          acc[ms][ns] = __builtin_amdgcn_mfma_f32_16x16x32_bf16(
              a[ms], breg[cur][kk][ns], acc[ms][ns], 0, 0, 0);
    }
  }

  // vectorized epilogue: acc -> Lf -> float4 stores with bias
  __syncthreads();
#pragma unroll
  for (int ms = 0; ms < 4; ++ms)
#pragma unroll
    for (int ns = 0; ns < 2; ++ns)
#pragma unroll
      for (int r = 0; r < 4; ++r)
        Lf[(ms * 16 + lg * 4 + r) * 132 + w * 32 + ns * 16 + lr] = acc[ms][ns][r];
  __syncthreads();
#pragma unroll
  for (int it = 0; it < 8; ++it) {
    const int row = (tid >> 3) + 32 * (it & 1);
    const int c4 = (tid & 7) + 8 * (it >> 1);   // 0..31 float4 chunks
    float4 v = *reinterpret_cast<const float4*>(&Lf[row * 132 + c4 * 4]);
    const float4 b4 = *reinterpret_cast<const float4*>(&bo[n0 + c4 * 4]);
    v.x += b4.x; v.y += b4.y; v.z += b4.z; v.w += b4.w;
    *reinterpret_cast<float4*>(&out[(size_t)(m0 + row) * EMB + n0 + c4 * 4]) = v;
  }
}

// ---------------- launcher ----------------
extern "C" void kernel_launch(void* const* d_in, const int* in_sizes, int n_in,
                              void* d_out, int out_size, void* d_ws, size_t ws_size,
                              hipStream_t stream) {
  const float* x  = (const float*)d_in[0];
  const float* Wq = (const float*)d_in[1];
  const float* Wk = (const float*)d_in[2];
  const float* Wv = (const float*)d_in[3];
  const float* Wo = (const float*)d_in[4];
  const float* bo = (const float*)d_in[5];
  float* out = (float*)d_out;

  uint8_t* ws = (uint8_t*)d_ws;
  unsigned short* Wqt = (unsigned short*)(ws + 12582912);
  unsigned short* Wkt = (unsigned short*)(ws + 12877824);
  unsigned short* Wvt = (unsigned short*)(ws + 13172736);
  unsigned short* Wot = (unsigned short*)(ws + 13467648);
  unsigned short* Qb  = (unsigned short*)(ws + 13762560);
  unsigned short* Kb  = (unsigned short*)(ws + 26345472);
  unsigned short* VT  = (unsigned short*)(ws + 38928384);      // [b,h,d,s]
  unsigned short* Ob  = (unsigned short*)(ws + 51511296);      // end 64094208

  hipLaunchKernelGGL(k_prepw, dim3(144), dim3(256), 0, stream,
                     Wq, Wk, Wv, Wo, Wqt, Wkt, Wvt, Wot);
  hipLaunchKernelGGL(k_qkv, dim3(128, 9), dim3(256), 0, stream,
                     x, Wqt, Wkt, Wvt, Qb, Kb, VT);
  hipLaunchKernelGGL(k_attn, dim3(16, 48), dim3(256), 0, stream, Qb, Kb, VT, Ob);
  hipLaunchKernelGGL(k_oproj, dim3(256, 3), dim3(256), 0, stream, Ob, Wot, bo, out);
}

// Round 9
// 191.118 us; speedup vs baseline: 1.0579x; 1.0579x over previous
//
#include <hip/hip_runtime.h>
#include <hip/hip_bf16.h>
#include <cstdint>
#include <cstddef>

typedef __attribute__((ext_vector_type(8))) short short8;
typedef __attribute__((ext_vector_type(4))) float f32x4;

#define S_LEN 2048
#define EMB 384
#define NH 6
#define HD 64
#define NB 8
// Q pre-scale: (1/sqrt(64)) * log2(e) so attn uses exp2 directly
#define QSCALE 0.180336880f

__device__ __forceinline__ unsigned short f2bf(float f) {
  return __builtin_bit_cast(unsigned short, __float2bfloat16(f));
}

// ---------------- prep: coalesced LDS W-transpose only ----------------
__global__ __launch_bounds__(256) void k_prepw(
    const float* __restrict__ Wq, const float* __restrict__ Wk,
    const float* __restrict__ Wv, const float* __restrict__ Wo,
    unsigned short* __restrict__ Wqt, unsigned short* __restrict__ Wkt,
    unsigned short* __restrict__ Wvt, unsigned short* __restrict__ Wot) {
  __shared__ unsigned short Lw[64 * 66];
  const int tid = threadIdx.x;
  const int bx2 = blockIdx.x;            // 0..143
  const int mat = bx2 / 36;
  const int tile = bx2 - mat * 36;
  const int k0 = (tile / 6) * 64;
  const int n0 = (tile % 6) * 64;
  const float* W = (mat == 0) ? Wq : (mat == 1) ? Wk : (mat == 2) ? Wv : Wo;
  unsigned short* Wt = (mat == 0) ? Wqt : (mat == 1) ? Wkt : (mat == 2) ? Wvt : Wot;
  const int f4 = tid & 15;
#pragma unroll
  for (int it = 0; it < 4; ++it) {
    const int kl = it * 16 + (tid >> 4);
    const float4 v = reinterpret_cast<const float4*>(W + (size_t)(k0 + kl) * EMB + n0)[f4];
    Lw[kl * 66 + f4 * 4 + 0] = f2bf(v.x);
    Lw[kl * 66 + f4 * 4 + 1] = f2bf(v.y);
    Lw[kl * 66 + f4 * 4 + 2] = f2bf(v.z);
    Lw[kl * 66 + f4 * 4 + 3] = f2bf(v.w);
  }
  __syncthreads();
  const int g = tid & 7;
#pragma unroll
  for (int it = 0; it < 2; ++it) {
    const int nl = it * 32 + (tid >> 3);
    short8 o;
#pragma unroll
    for (int j = 0; j < 8; ++j) o[j] = (short)Lw[(g * 8 + j) * 66 + nl];
    *reinterpret_cast<short8*>(Wt + (size_t)(n0 + nl) * EMB + k0 + g * 8) = o;
  }
}

// ---------------- fused QKV projection GEMM ----------------
__global__ __launch_bounds__(256) void k_qkv(
    const float* __restrict__ x,
    const unsigned short* __restrict__ Wqt,
    const unsigned short* __restrict__ Wkt,
    const unsigned short* __restrict__ Wvt,
    unsigned short* __restrict__ Qb,
    unsigned short* __restrict__ Kb,
    unsigned short* __restrict__ Vtb) {
  __shared__ __attribute__((aligned(16))) unsigned short La[128 * 72];   // A k-tile, pad 72
  __shared__ __attribute__((aligned(16))) unsigned short Lt[64 * 136];   // repack buffer

  const int tid = threadIdx.x;
  const int lane = tid & 63;
  const int w = tid >> 6;
  const int wr = w >> 1, wc = w & 1;
  const int lr = lane & 15, lg = lane >> 4;

  const int bid = blockIdx.y * 128 + blockIdx.x;
  const int xcd = bid & 7;
  const int pos = bid >> 3;            // 0..143
  const int bx = xcd * 16 + (pos & 15);
  const int by = pos >> 4;             // 0..8
  const int m0 = bx * 128;
  const int wsel = by / 3;
  const int n0 = (by % 3) * 128;
  const unsigned short* Wt = (wsel == 0) ? Wqt : (wsel == 1) ? Wkt : Wvt;

  const int srow = tid >> 3;       // 0..31
  const int sg = tid & 7;          // 16B slot

  f32x4 acc[4][4] = {};
  float4 xf[4][2];
  short8 breg[2][2][4];            // [parity][kk][frag]

#pragma unroll
  for (int i = 0; i < 4; ++i) {
    const float* src = x + (size_t)(m0 + i * 32 + srow) * EMB + sg * 8;
    xf[i][0] = *reinterpret_cast<const float4*>(src);
    xf[i][1] = *reinterpret_cast<const float4*>(src + 4);
  }
#pragma unroll
  for (int kk = 0; kk < 2; ++kk)
#pragma unroll
    for (int ns = 0; ns < 4; ++ns)
      breg[0][kk][ns] = *reinterpret_cast<const short8*>(
          Wt + (size_t)(n0 + wc * 64 + ns * 16 + lr) * EMB + kk * 32 + lg * 8);

#pragma unroll
  for (int kt = 0; kt < 6; ++kt) {
    const int cur = kt & 1, nxt = cur ^ 1;
    __syncthreads();
#pragma unroll
    for (int i = 0; i < 4; ++i) {
      short8 v;
      v[0] = (short)f2bf(xf[i][0].x); v[1] = (short)f2bf(xf[i][0].y);
      v[2] = (short)f2bf(xf[i][0].z); v[3] = (short)f2bf(xf[i][0].w);
      v[4] = (short)f2bf(xf[i][1].x); v[5] = (short)f2bf(xf[i][1].y);
      v[6] = (short)f2bf(xf[i][1].z); v[7] = (short)f2bf(xf[i][1].w);
      *reinterpret_cast<short8*>(&La[(i * 32 + srow) * 72 + sg * 8]) = v;
    }
    __syncthreads();
    if (kt < 5) {
      const int kn = (kt + 1) * 64;
#pragma unroll
      for (int i = 0; i < 4; ++i) {
        const float* src = x + (size_t)(m0 + i * 32 + srow) * EMB + kn + sg * 8;
        xf[i][0] = *reinterpret_cast<const float4*>(src);
        xf[i][1] = *reinterpret_cast<const float4*>(src + 4);
      }
#pragma unroll
      for (int kk = 0; kk < 2; ++kk)
#pragma unroll
        for (int ns = 0; ns < 4; ++ns)
          breg[nxt][kk][ns] = *reinterpret_cast<const short8*>(
              Wt + (size_t)(n0 + wc * 64 + ns * 16 + lr) * EMB + kn + kk * 32 + lg * 8);
    }
#pragma unroll
    for (int kk = 0; kk < 2; ++kk) {
      short8 a[4];
#pragma unroll
      for (int ms = 0; ms < 4; ++ms)
        a[ms] = *reinterpret_cast<const short8*>(
            &La[(wr * 64 + ms * 16 + lr) * 72 + kk * 32 + lg * 8]);
#pragma unroll
      for (int ms = 0; ms < 4; ++ms)
#pragma unroll
        for (int ns = 0; ns < 4; ++ns)
          acc[ms][ns] = __builtin_amdgcn_mfma_f32_16x16x32_bf16(
              a[ms], breg[cur][kk][ns], acc[ms][ns], 0, 0, 0);
    }
  }

  const int bb = m0 >> 11;
  const int s0 = m0 & 2047;
  if (wsel != 2) {
    unsigned short* Out = (wsel == 0) ? Qb : Kb;
    const float sc = (wsel == 0) ? QSCALE : 1.0f;
#pragma unroll
    for (int p = 0; p < 2; ++p) {
      __syncthreads();
      if (wr == p) {
#pragma unroll
        for (int ms = 0; ms < 4; ++ms)
#pragma unroll
          for (int ns = 0; ns < 4; ++ns)
#pragma unroll
            for (int r = 0; r < 4; ++r)
              Lt[(ms * 16 + lg * 4 + r) * 136 + wc * 64 + ns * 16 + lr] =
                  f2bf(acc[ms][ns][r] * sc);
      }
      __syncthreads();
#pragma unroll
      for (int it = 0; it < 4; ++it) {
        const int row = (tid >> 3) + 32 * (it & 1);
        const int ch = (tid & 7) + 8 * (it >> 1);
        const short8 v = *reinterpret_cast<const short8*>(&Lt[row * 136 + ch * 8]);
        const int n = n0 + ch * 8;
        const int h = n >> 6, d = n & 63;
        *reinterpret_cast<short8*>(
            Out + (((size_t)bb * NH + h) * S_LEN + (s0 + p * 64 + row)) * HD + d) = v;
      }
    }
  } else {
#pragma unroll
    for (int p = 0; p < 2; ++p) {
      __syncthreads();
      if (wc == p) {
#pragma unroll
        for (int ms = 0; ms < 4; ++ms)
#pragma unroll
          for (int ns = 0; ns < 4; ++ns)
#pragma unroll
            for (int r = 0; r < 4; ++r) {
              const int dl = ns * 16 + lr;                     // d 0..63
              const int ml = wr * 64 + ms * 16 + lg * 4 + r;   // m 0..127
              Lt[dl * 136 + (((ml >> 3) ^ (dl & 7)) << 3) + (ml & 7)] = f2bf(acc[ms][ns][r]);
            }
      }
      __syncthreads();
      const int hg = 2 * (n0 >> 7) + p;
      const int c = tid & 15;
#pragma unroll
      for (int it = 0; it < 4; ++it) {
        const int d = it * 16 + (tid >> 4);
        const short8 v = *reinterpret_cast<const short8*>(
            &Lt[d * 136 + ((c ^ (d & 7)) << 3)]);
        *reinterpret_cast<short8*>(
            Vtb + (((size_t)bb * NH + hg) * HD + d) * S_LEN + s0 + c * 8) = v;
      }
    }
  }
}

// ---------------- attn helper: one 64-KV tile for one q-tile set ----------------
__device__ __forceinline__ void attn_step(
    const unsigned short* __restrict__ K, const unsigned short* __restrict__ V,
    unsigned short* __restrict__ Ps,
    const short8 aq0, const short8 aq1,
    const int t, const int qt, const int qbase,
    const int w, const int lr, const int lg,
    f32x4* o, float* l_i) {
  const bool diag = (t == qt);
  const int kkmax = diag ? ((w >> 1) + 1) : 2;   // PV kk chunks needed
  const int ksmax = kkmax * 2;

  float sv[4][4];
#pragma unroll
  for (int ks = 0; ks < 4; ++ks) {
    if (!diag || ks <= w) {
      const int krow = ks * 16 + lr;
      const int kx = krow & 7;
      const short8 bk0 = *reinterpret_cast<const short8*>(&K[krow * 64 + ((lg ^ kx) << 3)]);
      const short8 bk1 = *reinterpret_cast<const short8*>(&K[krow * 64 + (((4 + lg) ^ kx) << 3)]);
      f32x4 s = {};
      s = __builtin_amdgcn_mfma_f32_16x16x32_bf16(aq0, bk0, s, 0, 0, 0);
      s = __builtin_amdgcn_mfma_f32_16x16x32_bf16(aq1, bk1, s, 0, 0, 0);
      if (diag && ks == w) {
#pragma unroll
        for (int r = 0; r < 4; ++r)
          sv[ks][r] = (lr <= lg * 4 + r) ? s[r] : -1e30f;
      } else {
#pragma unroll
        for (int r = 0; r < 4; ++r) sv[ks][r] = s[r];
      }
    }
  }

  // no-max softmax: p = exp2(s); zero-store pruned masked quads
#pragma unroll
  for (int r = 0; r < 4; ++r) {
    const int q = w * 16 + lg * 4 + r;
    const int qx = q & 7;
    const int abase = q * 64 + (lr & 7);
    const int sp = lr >> 3;
    float s = 0.f;
#pragma unroll
    for (int ks = 0; ks < 4; ++ks) {
      if (!diag || ks <= w) {
        const float p = __builtin_amdgcn_exp2f(sv[ks][r]);
        s += p;
        Ps[abase + ((((ks << 1) | sp) ^ qx) << 3)] = f2bf(p);
      } else if (ks < ksmax) {
        Ps[abase + ((((ks << 1) | sp) ^ qx) << 3)] = 0;
      }
    }
    l_i[r] += s;
  }

  // PV
  const int qrow = w * 16 + lr;
  const int qx2 = qrow & 7;
#pragma unroll
  for (int kk = 0; kk < 2; ++kk) {
    if (kk < kkmax) {
      const short8 ap = *reinterpret_cast<const short8*>(
          &Ps[qrow * 64 + (((kk * 4 + lg) ^ qx2) << 3)]);
#pragma unroll
      for (int ns = 0; ns < 4; ++ns) {
        const int vrow = ns * 16 + lr;
        const short8 bv = *reinterpret_cast<const short8*>(
            &V[vrow * 64 + (((kk * 4 + lg) ^ (vrow & 7)) << 3)]);
        o[ns] = __builtin_amdgcn_mfma_f32_16x16x32_bf16(ap, bv, o[ns], 0, 0, 0);
      }
    }
  }
}

// ---------------- causal flash attention: shared-sweep pair + dbuf LDS ----------------
// grid 768 XCD-swizzled; block 256 = 4 waves x 16 q-rows.
// Block serves q-tiles {pair, 31-pair} with ONE K/V sweep t=0..31-pair.
__global__ __launch_bounds__(256, 3) void k_attn(
    const unsigned short* __restrict__ Qb,
    const unsigned short* __restrict__ Kb,
    const unsigned short* __restrict__ Vtg,
    unsigned short* __restrict__ Ob) {
  __shared__ __attribute__((aligned(16))) unsigned short Ksb[2][64 * 64];
  __shared__ __attribute__((aligned(16))) unsigned short Vtb[2][64 * 64];
  __shared__ __attribute__((aligned(16))) unsigned short Psb[2][64 * 64];  // [set A/B]

  const int tid = threadIdx.x;
  const int lane = tid & 63;
  const int w = tid >> 6;
  const int lr = lane & 15, lg = lane >> 4;

  const int lin = blockIdx.y * 16 + blockIdx.x;
  const int swz = (lin & 7) * 96 + (lin >> 3);
  const int idx = swz & 15;
  const int bh = swz >> 4;
  // interleave pairs so neighboring blocks get mixed sweep lengths
  const int pair = (idx & 1) ? (15 - (idx >> 1)) : (idx >> 1);
  const int qtA = pair, qtB = 31 - pair;

  const unsigned short* Qp = Qb + (size_t)bh * S_LEN * HD;
  const unsigned short* Kp = Kb + (size_t)bh * S_LEN * HD;
  const unsigned short* Vp = Vtg + (size_t)bh * S_LEN * HD;
  const int b = bh / NH, hh = bh - b * NH;

  const int srow = tid >> 3;
  const int sslot = tid & 7;
  const int wsl0 = (sslot ^ (srow & 7)) << 3;

  const int qbA = qtA * 64 + w * 16;
  const int qbB = qtB * 64 + w * 16;

  const short8 aqA0 = *reinterpret_cast<const short8*>(Qp + (size_t)(qbA + lr) * HD + lg * 8);
  const short8 aqA1 = *reinterpret_cast<const short8*>(Qp + (size_t)(qbA + lr) * HD + 32 + lg * 8);
  const short8 aqB0 = *reinterpret_cast<const short8*>(Qp + (size_t)(qbB + lr) * HD + lg * 8);
  const short8 aqB1 = *reinterpret_cast<const short8*>(Qp + (size_t)(qbB + lr) * HD + 32 + lg * 8);

  f32x4 oA[4] = {}, oB[4] = {};
  float lA[4] = {0.f, 0.f, 0.f, 0.f}, lB[4] = {0.f, 0.f, 0.f, 0.f};

  // prologue: tile 0
  short8 pk0 = *reinterpret_cast<const short8*>(Kp + (size_t)srow * HD + sslot * 8);
  short8 pk1 = *reinterpret_cast<const short8*>(Kp + (size_t)(srow + 32) * HD + sslot * 8);
  short8 pv0 = *reinterpret_cast<const short8*>(Vp + (size_t)srow * S_LEN + sslot * 8);
  short8 pv1 = *reinterpret_cast<const short8*>(Vp + (size_t)(srow + 32) * S_LEN + sslot * 8);
  *reinterpret_cast<short8*>(&Ksb[0][srow * 64 + wsl0]) = pk0;
  *reinterpret_cast<short8*>(&Ksb[0][(srow + 32) * 64 + wsl0]) = pk1;
  *reinterpret_cast<short8*>(&Vtb[0][srow * 64 + wsl0]) = pv0;
  *reinterpret_cast<short8*>(&Vtb[0][(srow + 32) * 64 + wsl0]) = pv1;
  __syncthreads();

  for (int t = 0; t <= qtB; ++t) {
    const int cur = t & 1;
    const bool more = t < qtB;
    if (more) {  // issue next-tile loads under compute
      const int tn = (t + 1) * 64;
      pk0 = *reinterpret_cast<const short8*>(Kp + (size_t)(tn + srow) * HD + sslot * 8);
      pk1 = *reinterpret_cast<const short8*>(Kp + (size_t)(tn + srow + 32) * HD + sslot * 8);
      pv0 = *reinterpret_cast<const short8*>(Vp + (size_t)srow * S_LEN + tn + sslot * 8);
      pv1 = *reinterpret_cast<const short8*>(Vp + (size_t)(srow + 32) * S_LEN + tn + sslot * 8);
    }

    attn_step(Ksb[cur], Vtb[cur], Psb[1], aqB0, aqB1, t, qtB, qbB, w, lr, lg, oB, lB);
    if (t <= qtA)
      attn_step(Ksb[cur], Vtb[cur], Psb[0], aqA0, aqA1, t, qtA, qbA, w, lr, lg, oA, lA);

    if (more) {
      const int nxt = cur ^ 1;
      *reinterpret_cast<short8*>(&Ksb[nxt][srow * 64 + wsl0]) = pk0;
      *reinterpret_cast<short8*>(&Ksb[nxt][(srow + 32) * 64 + wsl0]) = pk1;
      *reinterpret_cast<short8*>(&Vtb[nxt][srow * 64 + wsl0]) = pv0;
      *reinterpret_cast<short8*>(&Vtb[nxt][(srow + 32) * 64 + wsl0]) = pv1;
    }
    __syncthreads();
  }

  // epilogue: both sets
#pragma unroll
  for (int r = 0; r < 4; ++r) {
    float la = lA[r], lb = lB[r];
    la += __shfl_xor(la, 1); lb += __shfl_xor(lb, 1);
    la += __shfl_xor(la, 2); lb += __shfl_xor(lb, 2);
    la += __shfl_xor(la, 4); lb += __shfl_xor(lb, 4);
    la += __shfl_xor(la, 8); lb += __shfl_xor(lb, 8);
    lA[r] = 1.0f / la; lB[r] = 1.0f / lb;
  }
#pragma unroll
  for (int ns = 0; ns < 4; ++ns)
#pragma unroll
    for (int r = 0; r < 4; ++r) {
      const int qgA = qbA + lg * 4 + r;
      const int qgB = qbB + lg * 4 + r;
      Ob[((size_t)(b * S_LEN + qgA)) * EMB + hh * HD + ns * 16 + lr] = f2bf(oA[ns][r] * lA[r]);
      Ob[((size_t)(b * S_LEN + qgB)) * EMB + hh * HD + ns * 16 + lr] = f2bf(oB[ns][r] * lB[r]);
    }
}

// ---------------- output projection (BM=64, vectorized epilogue) ----------------
__global__ __launch_bounds__(256) void k_oproj(
    const unsigned short* __restrict__ Ob,
    const unsigned short* __restrict__ Wot,
    const float* __restrict__ bo,
    float* __restrict__ out) {
  __shared__ __attribute__((aligned(16))) unsigned short La[64 * 72];
  __shared__ __attribute__((aligned(16))) float Lf[64 * 132];

  const int tid = threadIdx.x;
  const int lane = tid & 63;
  const int w = tid >> 6;
  const int lr = lane & 15, lg = lane >> 4;

  const int bid = blockIdx.y * 256 + blockIdx.x;
  const int xcd = bid & 7;
  const int pos = bid >> 3;            // 0..95
  const int m0 = (xcd * 32 + (pos & 31)) * 64;
  const int n0 = (pos >> 5) * 128;

  const int srow = tid >> 3;       // 0..31
  const int sg = tid & 7;

  f32x4 acc[4][2] = {};
  short8 st[2];
  short8 breg[2][2][2];            // [parity][kk][ns]

#pragma unroll
  for (int i = 0; i < 2; ++i)
    st[i] = *reinterpret_cast<const short8*>(
        Ob + (size_t)(m0 + i * 32 + srow) * EMB + sg * 8);
#pragma unroll
  for (int kk = 0; kk < 2; ++kk)
#pragma unroll
    for (int ns = 0; ns < 2; ++ns)
      breg[0][kk][ns] = *reinterpret_cast<const short8*>(
          Wot + (size_t)(n0 + w * 32 + ns * 16 + lr) * EMB + kk * 32 + lg * 8);

#pragma unroll
  for (int kt = 0; kt < 6; ++kt) {
    const int cur = kt & 1, nxt = cur ^ 1;
    __syncthreads();
#pragma unroll
    for (int i = 0; i < 2; ++i)
      *reinterpret_cast<short8*>(&La[(i * 32 + srow) * 72 + sg * 8]) = st[i];
    __syncthreads();
    if (kt < 5) {
      const int kn = (kt + 1) * 64;
#pragma unroll
      for (int i = 0; i < 2; ++i)
        st[i] = *reinterpret_cast<const short8*>(
            Ob + (size_t)(m0 + i * 32 + srow) * EMB + kn + sg * 8);
#pragma unroll
      for (int kk = 0; kk < 2; ++kk)
#pragma unroll
        for (int ns = 0; ns < 2; ++ns)
          breg[nxt][kk][ns] = *reinterpret_cast<const short8*>(
              Wot + (size_t)(n0 + w * 32 + ns * 16 + lr) * EMB + kn + kk * 32 + lg * 8);
    }
#pragma unroll
    for (int kk = 0; kk < 2; ++kk) {
      short8 a[4];
#pragma unroll
      for (int ms = 0; ms < 4; ++ms)
        a[ms] = *reinterpret_cast<const short8*>(
            &La[(ms * 16 + lr) * 72 + kk * 32 + lg * 8]);
#pragma unroll
      for (int ms = 0; ms < 4; ++ms)
#pragma unroll
        for (int ns = 0; ns < 2; ++ns)
          acc[ms][ns] = __builtin_amdgcn_mfma_f32_16x16x32_bf16(
              a[ms], breg[cur][kk][ns], acc[ms][ns], 0, 0, 0);
    }
  }

  __syncthreads();
#pragma unroll
  for (int ms = 0; ms < 4; ++ms)
#pragma unroll
    for (int ns = 0; ns < 2; ++ns)
#pragma unroll
      for (int r = 0; r < 4; ++r)
        Lf[(ms * 16 + lg * 4 + r) * 132 + w * 32 + ns * 16 + lr] = acc[ms][ns][r];
  __syncthreads();
#pragma unroll
  for (int it = 0; it < 8; ++it) {
    const int row = (tid >> 3) + 32 * (it & 1);
    const int c4 = (tid & 7) + 8 * (it >> 1);   // 0..31 float4 chunks
    float4 v = *reinterpret_cast<const float4*>(&Lf[row * 132 + c4 * 4]);
    const float4 b4 = *reinterpret_cast<const float4*>(&bo[n0 + c4 * 4]);
    v.x += b4.x; v.y += b4.y; v.z += b4.z; v.w += b4.w;
    *reinterpret_cast<float4*>(&out[(size_t)(m0 + row) * EMB + n0 + c4 * 4]) = v;
  }
}

// ---------------- launcher ----------------
extern "C" void kernel_launch(void* const* d_in, const int* in_sizes, int n_in,
                              void* d_out, int out_size, void* d_ws, size_t ws_size,
                              hipStream_t stream) {
  const float* x  = (const float*)d_in[0];
  const float* Wq = (const float*)d_in[1];
  const float* Wk = (const float*)d_in[2];
  const float* Wv = (const float*)d_in[3];
  const float* Wo = (const float*)d_in[4];
  const float* bo = (const float*)d_in[5];
  float* out = (float*)d_out;

  uint8_t* ws = (uint8_t*)d_ws;
  unsigned short* Wqt = (unsigned short*)(ws + 12582912);
  unsigned short* Wkt = (unsigned short*)(ws + 12877824);
  unsigned short* Wvt = (unsigned short*)(ws + 13172736);
  unsigned short* Wot = (unsigned short*)(ws + 13467648);
  unsigned short* Qb  = (unsigned short*)(ws + 13762560);
  unsigned short* Kb  = (unsigned short*)(ws + 26345472);
  unsigned short* VT  = (unsigned short*)(ws + 38928384);      // [b,h,d,s]
  unsigned short* Ob  = (unsigned short*)(ws + 51511296);      // end 64094208

  hipLaunchKernelGGL(k_prepw, dim3(144), dim3(256), 0, stream,
                     Wq, Wk, Wv, Wo, Wqt, Wkt, Wvt, Wot);
  hipLaunchKernelGGL(k_qkv, dim3(128, 9), dim3(256), 0, stream,
                     x, Wqt, Wkt, Wvt, Qb, Kb, VT);
  hipLaunchKernelGGL(k_attn, dim3(16, 48), dim3(256), 0, stream, Qb, Kb, VT, Ob);
  hipLaunchKernelGGL(k_oproj, dim3(256, 3), dim3(256), 0, stream, Ob, Wot, bo, out);
}

// Round 10
// 183.926 us; speedup vs baseline: 1.0993x; 1.0391x over previous
//
#include <hip/hip_runtime.h>
#include <hip/hip_bf16.h>
#include <cstdint>
#include <cstddef>

typedef __attribute__((ext_vector_type(8))) short short8;
typedef __attribute__((ext_vector_type(4))) float f32x4;

#define S_LEN 2048
#define EMB 384
#define NH 6
#define HD 64
#define NB 8
// Q pre-scale: (1/sqrt(64)) * log2(e) so attn uses exp2 directly
#define QSCALE 0.180336880f

__device__ __forceinline__ unsigned short f2bf(float f) {
  return __builtin_bit_cast(unsigned short, __float2bfloat16(f));
}

// ---------------- prep: coalesced LDS W-transpose only ----------------
__global__ __launch_bounds__(256) void k_prepw(
    const float* __restrict__ Wq, const float* __restrict__ Wk,
    const float* __restrict__ Wv, const float* __restrict__ Wo,
    unsigned short* __restrict__ Wqt, unsigned short* __restrict__ Wkt,
    unsigned short* __restrict__ Wvt, unsigned short* __restrict__ Wot) {
  __shared__ unsigned short Lw[64 * 66];
  const int tid = threadIdx.x;
  const int bx2 = blockIdx.x;            // 0..143
  const int mat = bx2 / 36;
  const int tile = bx2 - mat * 36;
  const int k0 = (tile / 6) * 64;
  const int n0 = (tile % 6) * 64;
  const float* W = (mat == 0) ? Wq : (mat == 1) ? Wk : (mat == 2) ? Wv : Wo;
  unsigned short* Wt = (mat == 0) ? Wqt : (mat == 1) ? Wkt : (mat == 2) ? Wvt : Wot;
  const int f4 = tid & 15;
#pragma unroll
  for (int it = 0; it < 4; ++it) {
    const int kl = it * 16 + (tid >> 4);
    const float4 v = reinterpret_cast<const float4*>(W + (size_t)(k0 + kl) * EMB + n0)[f4];
    Lw[kl * 66 + f4 * 4 + 0] = f2bf(v.x);
    Lw[kl * 66 + f4 * 4 + 1] = f2bf(v.y);
    Lw[kl * 66 + f4 * 4 + 2] = f2bf(v.z);
    Lw[kl * 66 + f4 * 4 + 3] = f2bf(v.w);
  }
  __syncthreads();
  const int g = tid & 7;
#pragma unroll
  for (int it = 0; it < 2; ++it) {
    const int nl = it * 32 + (tid >> 3);
    short8 o;
#pragma unroll
    for (int j = 0; j < 8; ++j) o[j] = (short)Lw[(g * 8 + j) * 66 + nl];
    *reinterpret_cast<short8*>(Wt + (size_t)(n0 + nl) * EMB + k0 + g * 8) = o;
  }
}

// ---------------- fused QKV projection GEMM ----------------
__global__ __launch_bounds__(256) void k_qkv(
    const float* __restrict__ x,
    const unsigned short* __restrict__ Wqt,
    const unsigned short* __restrict__ Wkt,
    const unsigned short* __restrict__ Wvt,
    unsigned short* __restrict__ Qb,
    unsigned short* __restrict__ Kb,
    unsigned short* __restrict__ Vtb) {
  __shared__ __attribute__((aligned(16))) unsigned short La[128 * 72];   // A k-tile, pad 72
  __shared__ __attribute__((aligned(16))) unsigned short Lt[64 * 136];   // repack buffer

  const int tid = threadIdx.x;
  const int lane = tid & 63;
  const int w = tid >> 6;
  const int wr = w >> 1, wc = w & 1;
  const int lr = lane & 15, lg = lane >> 4;

  const int bid = blockIdx.y * 128 + blockIdx.x;
  const int xcd = bid & 7;
  const int pos = bid >> 3;            // 0..143
  const int bx = xcd * 16 + (pos & 15);
  const int by = pos >> 4;             // 0..8
  const int m0 = bx * 128;
  const int wsel = by / 3;
  const int n0 = (by % 3) * 128;
  const unsigned short* Wt = (wsel == 0) ? Wqt : (wsel == 1) ? Wkt : Wvt;

  const int srow = tid >> 3;       // 0..31
  const int sg = tid & 7;          // 16B slot

  f32x4 acc[4][4] = {};
  float4 xf[4][2];
  short8 breg[2][2][4];            // [parity][kk][frag]

#pragma unroll
  for (int i = 0; i < 4; ++i) {
    const float* src = x + (size_t)(m0 + i * 32 + srow) * EMB + sg * 8;
    xf[i][0] = *reinterpret_cast<const float4*>(src);
    xf[i][1] = *reinterpret_cast<const float4*>(src + 4);
  }
#pragma unroll
  for (int kk = 0; kk < 2; ++kk)
#pragma unroll
    for (int ns = 0; ns < 4; ++ns)
      breg[0][kk][ns] = *reinterpret_cast<const short8*>(
          Wt + (size_t)(n0 + wc * 64 + ns * 16 + lr) * EMB + kk * 32 + lg * 8);

#pragma unroll
  for (int kt = 0; kt < 6; ++kt) {
    const int cur = kt & 1, nxt = cur ^ 1;
    __syncthreads();
#pragma unroll
    for (int i = 0; i < 4; ++i) {
      short8 v;
      v[0] = (short)f2bf(xf[i][0].x); v[1] = (short)f2bf(xf[i][0].y);
      v[2] = (short)f2bf(xf[i][0].z); v[3] = (short)f2bf(xf[i][0].w);
      v[4] = (short)f2bf(xf[i][1].x); v[5] = (short)f2bf(xf[i][1].y);
      v[6] = (short)f2bf(xf[i][1].z); v[7] = (short)f2bf(xf[i][1].w);
      *reinterpret_cast<short8*>(&La[(i * 32 + srow) * 72 + sg * 8]) = v;
    }
    __syncthreads();
    if (kt < 5) {
      const int kn = (kt + 1) * 64;
#pragma unroll
      for (int i = 0; i < 4; ++i) {
        const float* src = x + (size_t)(m0 + i * 32 + srow) * EMB + kn + sg * 8;
        xf[i][0] = *reinterpret_cast<const float4*>(src);
        xf[i][1] = *reinterpret_cast<const float4*>(src + 4);
      }
#pragma unroll
      for (int kk = 0; kk < 2; ++kk)
#pragma unroll
        for (int ns = 0; ns < 4; ++ns)
          breg[nxt][kk][ns] = *reinterpret_cast<const short8*>(
              Wt + (size_t)(n0 + wc * 64 + ns * 16 + lr) * EMB + kn + kk * 32 + lg * 8);
    }
#pragma unroll
    for (int kk = 0; kk < 2; ++kk) {
      short8 a[4];
#pragma unroll
      for (int ms = 0; ms < 4; ++ms)
        a[ms] = *reinterpret_cast<const short8*>(
            &La[(wr * 64 + ms * 16 + lr) * 72 + kk * 32 + lg * 8]);
#pragma unroll
      for (int ms = 0; ms < 4; ++ms)
#pragma unroll
        for (int ns = 0; ns < 4; ++ns)
          acc[ms][ns] = __builtin_amdgcn_mfma_f32_16x16x32_bf16(
              a[ms], breg[cur][kk][ns], acc[ms][ns], 0, 0, 0);
    }
  }

  const int bb = m0 >> 11;
  const int s0 = m0 & 2047;
  if (wsel != 2) {
    unsigned short* Out = (wsel == 0) ? Qb : Kb;
    const float sc = (wsel == 0) ? QSCALE : 1.0f;
#pragma unroll
    for (int p = 0; p < 2; ++p) {
      __syncthreads();
      if (wr == p) {
#pragma unroll
        for (int ms = 0; ms < 4; ++ms)
#pragma unroll
          for (int ns = 0; ns < 4; ++ns)
#pragma unroll
            for (int r = 0; r < 4; ++r)
              Lt[(ms * 16 + lg * 4 + r) * 136 + wc * 64 + ns * 16 + lr] =
                  f2bf(acc[ms][ns][r] * sc);
      }
      __syncthreads();
#pragma unroll
      for (int it = 0; it < 4; ++it) {
        const int row = (tid >> 3) + 32 * (it & 1);
        const int ch = (tid & 7) + 8 * (it >> 1);
        const short8 v = *reinterpret_cast<const short8*>(&Lt[row * 136 + ch * 8]);
        const int n = n0 + ch * 8;
        const int h = n >> 6, d = n & 63;
        *reinterpret_cast<short8*>(
            Out + (((size_t)bb * NH + h) * S_LEN + (s0 + p * 64 + row)) * HD + d) = v;
      }
    }
  } else {
#pragma unroll
    for (int p = 0; p < 2; ++p) {
      __syncthreads();
      if (wc == p) {
#pragma unroll
        for (int ms = 0; ms < 4; ++ms)
#pragma unroll
          for (int ns = 0; ns < 4; ++ns)
#pragma unroll
            for (int r = 0; r < 4; ++r) {
              const int dl = ns * 16 + lr;                     // d 0..63
              const int ml = wr * 64 + ms * 16 + lg * 4 + r;   // m 0..127
              Lt[dl * 136 + (((ml >> 3) ^ (dl & 7)) << 3) + (ml & 7)] = f2bf(acc[ms][ns][r]);
            }
      }
      __syncthreads();
      const int hg = 2 * (n0 >> 7) + p;
      const int c = tid & 15;
#pragma unroll
      for (int it = 0; it < 4; ++it) {
        const int d = it * 16 + (tid >> 4);
        const short8 v = *reinterpret_cast<const short8*>(
            &Lt[d * 136 + ((c ^ (d & 7)) << 3)]);
        *reinterpret_cast<short8*>(
            Vtb + (((size_t)bb * NH + hg) * HD + d) * S_LEN + s0 + c * 8) = v;
      }
    }
  }
}

// ---------------- causal flash attention ----------------
// Shared-sweep pair + dbuf LDS + swapped QK^T (P lane-local in kv) +
// K/V fragments shared between the two q-tile sets.
// grid 768 XCD-swizzled; block 256 = 4 waves x 16 q-rows.
__global__ __launch_bounds__(256, 3) void k_attn(
    const unsigned short* __restrict__ Qb,
    const unsigned short* __restrict__ Kb,
    const unsigned short* __restrict__ Vtg,
    unsigned short* __restrict__ Ob) {
  __shared__ __attribute__((aligned(16))) unsigned short Ksb[2][64 * 64];
  __shared__ __attribute__((aligned(16))) unsigned short Vtb[2][64 * 64];
  __shared__ __attribute__((aligned(16))) unsigned short PsA[64 * 64];
  __shared__ __attribute__((aligned(16))) unsigned short PsB[64 * 64];

  const int tid = threadIdx.x;
  const int lane = tid & 63;
  const int w = tid >> 6;
  const int lr = lane & 15, lg = lane >> 4;

  const int lin = blockIdx.y * 16 + blockIdx.x;
  const int swz = (lin & 7) * 96 + (lin >> 3);
  const int idx = swz & 15;
  const int bh = swz >> 4;
  const int pair = (idx & 1) ? (15 - (idx >> 1)) : (idx >> 1);
  const int qtA = pair, qtB = 31 - pair;

  const unsigned short* Qp = Qb + (size_t)bh * S_LEN * HD;
  const unsigned short* Kp = Kb + (size_t)bh * S_LEN * HD;
  const unsigned short* Vp = Vtg + (size_t)bh * S_LEN * HD;
  const int b = bh / NH, hh = bh - b * NH;

  const int srow = tid >> 3;
  const int sslot = tid & 7;
  const int wsl0 = (sslot ^ (srow & 7)) << 3;

  const int qbA = qtA * 64 + w * 16;
  const int qbB = qtB * 64 + w * 16;

  const short8 aqA0 = *reinterpret_cast<const short8*>(Qp + (size_t)(qbA + lr) * HD + lg * 8);
  const short8 aqA1 = *reinterpret_cast<const short8*>(Qp + (size_t)(qbA + lr) * HD + 32 + lg * 8);
  const short8 aqB0 = *reinterpret_cast<const short8*>(Qp + (size_t)(qbB + lr) * HD + lg * 8);
  const short8 aqB1 = *reinterpret_cast<const short8*>(Qp + (size_t)(qbB + lr) * HD + 32 + lg * 8);

  f32x4 oA[4] = {}, oB[4] = {};
  float lA = 0.f, lB = 0.f;

  // P tile addressing (swapped layout): row q = w*16+lr; per-ks write slot.
  const int prow = (w * 16 + lr) * 64;
  const int pmask = lr & 7;            // XOR swizzle mask (q&7)
  const int ph = (lg & 1) * 4;         // u16 offset of the b64 half
  const int ptb = lg >> 1;             // t' base: slot16 = 2*ks + (lg>>1)

  // prologue: tile 0
  short8 pk0 = *reinterpret_cast<const short8*>(Kp + (size_t)srow * HD + sslot * 8);
  short8 pk1 = *reinterpret_cast<const short8*>(Kp + (size_t)(srow + 32) * HD + sslot * 8);
  short8 pv0 = *reinterpret_cast<const short8*>(Vp + (size_t)srow * S_LEN + sslot * 8);
  short8 pv1 = *reinterpret_cast<const short8*>(Vp + (size_t)(srow + 32) * S_LEN + sslot * 8);
  *reinterpret_cast<short8*>(&Ksb[0][srow * 64 + wsl0]) = pk0;
  *reinterpret_cast<short8*>(&Ksb[0][(srow + 32) * 64 + wsl0]) = pk1;
  *reinterpret_cast<short8*>(&Vtb[0][srow * 64 + wsl0]) = pv0;
  *reinterpret_cast<short8*>(&Vtb[0][(srow + 32) * 64 + wsl0]) = pv1;
  __syncthreads();

  for (int t = 0; t <= qtB; ++t) {
    const int cur = t & 1;
    const bool more = t < qtB;
    if (more) {
      const int tn = (t + 1) * 64;
      pk0 = *reinterpret_cast<const short8*>(Kp + (size_t)(tn + srow) * HD + sslot * 8);
      pk1 = *reinterpret_cast<const short8*>(Kp + (size_t)(tn + srow + 32) * HD + sslot * 8);
      pv0 = *reinterpret_cast<const short8*>(Vp + (size_t)srow * S_LEN + tn + sslot * 8);
      pv1 = *reinterpret_cast<const short8*>(Vp + (size_t)(srow + 32) * S_LEN + tn + sslot * 8);
    }

    const unsigned short* Ks = Ksb[cur];
    const unsigned short* Vt = Vtb[cur];
    const bool doA = (t <= qtA);
    const bool diagA = (t == qtA);
    const bool diagB = (t == qtB);

    // shared K fragments (A-operand: rows = kv)
    short8 kf0[4], kf1[4];
#pragma unroll
    for (int ks = 0; ks < 4; ++ks) {
      const int krow = ks * 16 + lr;
      const int kx = krow & 7;
      kf0[ks] = *reinterpret_cast<const short8*>(&Ks[krow * 64 + ((lg ^ kx) << 3)]);
      kf1[ks] = *reinterpret_cast<const short8*>(&Ks[krow * 64 + (((4 + lg) ^ kx) << 3)]);
    }

    // QK^T (swapped: s[r] = S[kv=16ks+4lg+r][q=lr]) + softmax + packed P store
    auto qkt_set = [&](const short8& aq0, const short8& aq1,
                       unsigned short* Ps, float& lsum, const bool diag) {
      const int kkm2 = diag ? (((w >> 1) + 1) << 1) : 4;
#pragma unroll
      for (int ks = 0; ks < 4; ++ks) {
        unsigned short* pp = Ps + prow + (((2 * ks + ptb) ^ pmask) << 3) + ph;
        if (!diag || ks <= w) {
          f32x4 s = {};
          s = __builtin_amdgcn_mfma_f32_16x16x32_bf16(kf0[ks], aq0, s, 0, 0, 0);
          s = __builtin_amdgcn_mfma_f32_16x16x32_bf16(kf1[ks], aq1, s, 0, 0, 0);
          float p[4];
          if (diag && ks == w) {
#pragma unroll
            for (int r = 0; r < 4; ++r)
              p[r] = (4 * lg + r <= lr) ? __builtin_amdgcn_exp2f(s[r]) : 0.f;
          } else {
#pragma unroll
            for (int r = 0; r < 4; ++r) p[r] = __builtin_amdgcn_exp2f(s[r]);
          }
          lsum += (p[0] + p[1]) + (p[2] + p[3]);
          uint2 pkd;
          pkd.x = ((unsigned)f2bf(p[1]) << 16) | (unsigned)f2bf(p[0]);
          pkd.y = ((unsigned)f2bf(p[3]) << 16) | (unsigned)f2bf(p[2]);
          *reinterpret_cast<uint2*>(pp) = pkd;
        } else if (ks < kkm2) {
          *reinterpret_cast<uint2*>(pp) = make_uint2(0u, 0u);
        }
      }
    };

    qkt_set(aqB0, aqB1, PsB, lB, diagB);
    if (doA) qkt_set(aqA0, aqA1, PsA, lA, diagA);

    // shared V fragments (B-operand: rows = d)
    short8 vf0[4], vf1[4];
#pragma unroll
    for (int ns = 0; ns < 4; ++ns) {
      const int vrow = ns * 16 + lr;
      const int vx = vrow & 7;
      vf0[ns] = *reinterpret_cast<const short8*>(&Vt[vrow * 64 + ((lg ^ vx) << 3)]);
      vf1[ns] = *reinterpret_cast<const short8*>(&Vt[vrow * 64 + (((4 + lg) ^ vx) << 3)]);
    }

    auto pv_set = [&](const unsigned short* Ps, f32x4* o, const bool diag) {
      const int kkm = diag ? ((w >> 1) + 1) : 2;
      {
        const short8 ap = *reinterpret_cast<const short8*>(
            &Ps[prow + ((lg ^ pmask) << 3)]);
#pragma unroll
        for (int ns = 0; ns < 4; ++ns)
          o[ns] = __builtin_amdgcn_mfma_f32_16x16x32_bf16(ap, vf0[ns], o[ns], 0, 0, 0);
      }
      if (kkm > 1) {
        const short8 ap = *reinterpret_cast<const short8*>(
            &Ps[prow + (((4 + lg) ^ pmask) << 3)]);
#pragma unroll
        for (int ns = 0; ns < 4; ++ns)
          o[ns] = __builtin_amdgcn_mfma_f32_16x16x32_bf16(ap, vf1[ns], o[ns], 0, 0, 0);
      }
    };

    pv_set(PsB, oB, diagB);
    if (doA) pv_set(PsA, oA, diagA);

    if (more) {
      const int nxt = cur ^ 1;
      *reinterpret_cast<short8*>(&Ksb[nxt][srow * 64 + wsl0]) = pk0;
      *reinterpret_cast<short8*>(&Ksb[nxt][(srow + 32) * 64 + wsl0]) = pk1;
      *reinterpret_cast<short8*>(&Vtb[nxt][srow * 64 + wsl0]) = pv0;
      *reinterpret_cast<short8*>(&Vtb[nxt][(srow + 32) * 64 + wsl0]) = pv1;
    }
    __syncthreads();
  }

  // epilogue: reduce l across lg groups (lanes lr, lr+16, lr+32, lr+48)
  lA += __shfl_xor(lA, 16); lA += __shfl_xor(lA, 32);
  lB += __shfl_xor(lB, 16); lB += __shfl_xor(lB, 32);
  const float liA = 1.0f / lA;
  const float liB = 1.0f / lB;
  float liAr[4], liBr[4];
#pragma unroll
  for (int r = 0; r < 4; ++r) {
    liAr[r] = __shfl(liA, 4 * lg + r);
    liBr[r] = __shfl(liB, 4 * lg + r);
  }
#pragma unroll
  for (int ns = 0; ns < 4; ++ns)
#pragma unroll
    for (int r = 0; r < 4; ++r) {
      const int qgA = qbA + lg * 4 + r;
      const int qgB = qbB + lg * 4 + r;
      Ob[((size_t)(b * S_LEN + qgA)) * EMB + hh * HD + ns * 16 + lr] = f2bf(oA[ns][r] * liAr[r]);
      Ob[((size_t)(b * S_LEN + qgB)) * EMB + hh * HD + ns * 16 + lr] = f2bf(oB[ns][r] * liBr[r]);
    }
}

// ---------------- output projection (BM=64, vectorized epilogue) ----------------
__global__ __launch_bounds__(256) void k_oproj(
    const unsigned short* __restrict__ Ob,
    const unsigned short* __restrict__ Wot,
    const float* __restrict__ bo,
    float* __restrict__ out) {
  __shared__ __attribute__((aligned(16))) unsigned short La[64 * 72];
  __shared__ __attribute__((aligned(16))) float Lf[64 * 132];

  const int tid = threadIdx.x;
  const int lane = tid & 63;
  const int w = tid >> 6;
  const int lr = lane & 15, lg = lane >> 4;

  const int bid = blockIdx.y * 256 + blockIdx.x;
  const int xcd = bid & 7;
  const int pos = bid >> 3;            // 0..95
  const int m0 = (xcd * 32 + (pos & 31)) * 64;
  const int n0 = (pos >> 5) * 128;

  const int srow = tid >> 3;       // 0..31
  const int sg = tid & 7;

  f32x4 acc[4][2] = {};
  short8 st[2];
  short8 breg[2][2][2];            // [parity][kk][ns]

#pragma unroll
  for (int i = 0; i < 2; ++i)
    st[i] = *reinterpret_cast<const short8*>(
        Ob + (size_t)(m0 + i * 32 + srow) * EMB + sg * 8);
#pragma unroll
  for (int kk = 0; kk < 2; ++kk)
#pragma unroll
    for (int ns = 0; ns < 2; ++ns)
      breg[0][kk][ns] = *reinterpret_cast<const short8*>(
          Wot + (size_t)(n0 + w * 32 + ns * 16 + lr) * EMB + kk * 32 + lg * 8);

#pragma unroll
  for (int kt = 0; kt < 6; ++kt) {
    const int cur = kt & 1, nxt = cur ^ 1;
    __syncthreads();
#pragma unroll
    for (int i = 0; i < 2; ++i)
      *reinterpret_cast<short8*>(&La[(i * 32 + srow) * 72 + sg * 8]) = st[i];
    __syncthreads();
    if (kt < 5) {
      const int kn = (kt + 1) * 64;
#pragma unroll
      for (int i = 0; i < 2; ++i)
        st[i] = *reinterpret_cast<const short8*>(
            Ob + (size_t)(m0 + i * 32 + srow) * EMB + kn + sg * 8);
#pragma unroll
      for (int kk = 0; kk < 2; ++kk)
#pragma unroll
        for (int ns = 0; ns < 2; ++ns)
          breg[nxt][kk][ns] = *reinterpret_cast<const short8*>(
              Wot + (size_t)(n0 + w * 32 + ns * 16 + lr) * EMB + kn + kk * 32 + lg * 8);
    }
#pragma unroll
    for (int kk = 0; kk < 2; ++kk) {
      short8 a[4];
#pragma unroll
      for (int ms = 0; ms < 4; ++ms)
        a[ms] = *reinterpret_cast<const short8*>(
            &La[(ms * 16 + lr) * 72 + kk * 32 + lg * 8]);
#pragma unroll
      for (int ms = 0; ms < 4; ++ms)
#pragma unroll
        for (int ns = 0; ns < 2; ++ns)
          acc[ms][ns] = __builtin_amdgcn_mfma_f32_16x16x32_bf16(
              a[ms], breg[cur][kk][ns], acc[ms][ns], 0, 0, 0);
    }
  }

  __syncthreads();
#pragma unroll
  for (int ms = 0; ms < 4; ++ms)
#pragma unroll
    for (int ns = 0; ns < 2; ++ns)
#pragma unroll
      for (int r = 0; r < 4; ++r)
        Lf[(ms * 16 + lg * 4 + r) * 132 + w * 32 + ns * 16 + lr] = acc[ms][ns][r];
  __syncthreads();
#pragma unroll
  for (int it = 0; it < 8; ++it) {
    const int row = (tid >> 3) + 32 * (it & 1);
    const int c4 = (tid & 7) + 8 * (it >> 1);   // 0..31 float4 chunks
    float4 v = *reinterpret_cast<const float4*>(&Lf[row * 132 + c4 * 4]);
    const float4 b4 = *reinterpret_cast<const float4*>(&bo[n0 + c4 * 4]);
    v.x += b4.x; v.y += b4.y; v.z += b4.z; v.w += b4.w;
    *reinterpret_cast<float4*>(&out[(size_t)(m0 + row) * EMB + n0 + c4 * 4]) = v;
  }
}

// ---------------- launcher ----------------
extern "C" void kernel_launch(void* const* d_in, const int* in_sizes, int n_in,
                              void* d_out, int out_size, void* d_ws, size_t ws_size,
                              hipStream_t stream) {
  const float* x  = (const float*)d_in[0];
  const float* Wq = (const float*)d_in[1];
  const float* Wk = (const float*)d_in[2];
  const float* Wv = (const float*)d_in[3];
  const float* Wo = (const float*)d_in[4];
  const float* bo = (const float*)d_in[5];
  float* out = (float*)d_out;

  uint8_t* ws = (uint8_t*)d_ws;
  unsigned short* Wqt = (unsigned short*)(ws + 12582912);
  unsigned short* Wkt = (unsigned short*)(ws + 12877824);
  unsigned short* Wvt = (unsigned short*)(ws + 13172736);
  unsigned short* Wot = (unsigned short*)(ws + 13467648);
  unsigned short* Qb  = (unsigned short*)(ws + 13762560);
  unsigned short* Kb  = (unsigned short*)(ws + 26345472);
  unsigned short* VT  = (unsigned short*)(ws + 38928384);      // [b,h,d,s]
  unsigned short* Ob  = (unsigned short*)(ws + 51511296);      // end 64094208

  hipLaunchKernelGGL(k_prepw, dim3(144), dim3(256), 0, stream,
                     Wq, Wk, Wv, Wo, Wqt, Wkt, Wvt, Wot);
  hipLaunchKernelGGL(k_qkv, dim3(128, 9), dim3(256), 0, stream,
                     x, Wqt, Wkt, Wvt, Qb, Kb, VT);
  hipLaunchKernelGGL(k_attn, dim3(16, 48), dim3(256), 0, stream, Qb, Kb, VT, Ob);
  hipLaunchKernelGGL(k_oproj, dim3(256, 3), dim3(256), 0, stream, Ob, Wot, bo, out);
}